// Round 17
// baseline (2435.947 us; speedup 1.0000x reference)
//
#include <hip/hip_runtime.h>
#include <hip/hip_bf16.h>
#include <cstdint>

typedef __attribute__((ext_vector_type(4))) float f32x4;
typedef _Float16 f16x8 __attribute__((ext_vector_type(8)));
typedef _Float16 f16x4 __attribute__((ext_vector_type(4)));

#define BN_EPS 1e-5f

// ---------------- fp32 -> fp16 cast (only W, 4 MB) ----------------
__global__ __launch_bounds__(256)
void cast_f32_f16(const float* __restrict__ src, _Float16* __restrict__ dst, int n8) {
    int i = blockIdx.x * blockDim.x + threadIdx.x;
    if (i >= n8) return;
    const float4* s4 = (const float4*)src;
    float4 a = s4[2 * (size_t)i];
    float4 b = s4[2 * (size_t)i + 1];
    f16x8 h;
    h[0] = (_Float16)a.x; h[1] = (_Float16)a.y; h[2] = (_Float16)a.z; h[3] = (_Float16)a.w;
    h[4] = (_Float16)b.x; h[5] = (_Float16)b.y; h[6] = (_Float16)b.z; h[7] = (_Float16)b.w;
    *(f16x8*)(dst + 8 * (size_t)i) = h;
}

// async global->LDS, 16B per lane, wave-uniform LDS base (B path)
__device__ __forceinline__ void async16(const char* g, char* l) {
    __builtin_amdgcn_global_load_lds(
        (const __attribute__((address_space(1))) unsigned int*)(uintptr_t)g,
        (__attribute__((address_space(3))) unsigned int*)(uintptr_t)l,
        16, 0, 0);
}

// ====== r16 core at 80KB LDS -> 2 blocks/CU (m114 inter-block overlap) ======
// A 2x16KB (write A(kt+1)@kt -> buf (kt-1)&1, reads drained at barrier kt-1: safe),
// B 3x16KB depth-2 (stage B(kt+2)). A-regs depth-2 (load A(kt+3), rA0/rA1 alternate).
// FIFO ledger per wave (order per iter: 4 A-loads, then 2 B-asyncs):
//   entering kt: outstanding = [A(kt+2)4, B(kt+1)2]
//   (a) cvt+write A(kt+1) (already retired by (f)@kt-1 -> no stall)
//   (b) A(kt+3)->rA[s]  (c) B(kt+2) asyncs   [outstanding 12]
//   (d) 12 ds_read (e) 32 MFMA
//   (f) vmcnt(6): retires A(kt+2)+B(kt+1) -> leaves [A(kt+3)4, B(kt+2)2]
//   (g) lgkmcnt(0) [A-writes visible]; barrier
// Tails: nt-3 -> vmcnt(2) (retires A(nt-1)+B(nt-2)); nt-2 -> vmcnt(0); nt-1 compute only.
// Prologue: A(0),B(0),A(1),B(1),cvt A(0),A(2) -> vmcnt(10) retires B(0).
// __launch_bounds__(512,4) pins VGPR<=128 so 4 waves/SIMD (2 blocks) fit.

#define ABUF(t) (lds + ((t) & 1) * 16384)
#define BBUF(t) (lds + 32768 + ((t) % 3) * 16384)

__device__ __forceinline__ void cvtWrite(char* addr, const f32x4& v) {
    f16x4 h;
    h[0] = (_Float16)v[0]; h[1] = (_Float16)v[1];
    h[2] = (_Float16)v[2]; h[3] = (_Float16)v[3];
    *(f16x4*)addr = h;
}

template<int WAITN, bool STAGEA, bool STAGEB, bool WRITEA, bool BAR>
__device__ __forceinline__ void ktile(
    int kt, char* lds, const float* aBase, size_t aRowStep,
    const char* b0, const char* b1, int widB,
    int aoff, int boff, const int (&wA)[4], f32x4 (&rAs)[4],
    f32x4 (&acc)[8][4])
{
    // (a) cvt + ds_write A(kt+1)
    if (WRITEA) {
        char* ad = ABUF(kt + 1);
        #pragma unroll
        for (int j = 0; j < 4; ++j) cvtWrite(ad + wA[j], rAs[j]);
    }
    // (b) A(kt+3) -> freed slot
    if (STAGEA) {
        #pragma unroll
        for (int j = 0; j < 4; ++j)
            rAs[j] = *(const f32x4*)(aBase + j * aRowStep + (size_t)(kt + 3) * 32);
    }
    // (c) B(kt+2) asyncs
    if (STAGEB) {
        char* d = BBUF(kt + 2) + widB;
        async16(b0 + (size_t)(kt + 2) * 64, d);
        async16(b1 + (size_t)(kt + 2) * 64, d + 8192);
    }
    // (d) fragment reads
    f16x8 a[8], b[4];
    const char* ab = ABUF(kt);
    const char* bb = BBUF(kt);
    #pragma unroll
    for (int n = 0; n < 4; ++n) b[n] = *(const f16x8*)(bb + boff + n * 1024);
    #pragma unroll
    for (int m = 0; m < 8; ++m) a[m] = *(const f16x8*)(ab + aoff + m * 1024);
    // (e) MFMA
    __builtin_amdgcn_s_setprio(1);
    #pragma unroll
    for (int m = 0; m < 8; ++m)
        #pragma unroll
        for (int n = 0; n < 4; ++n)
            acc[m][n] = __builtin_amdgcn_mfma_f32_16x16x32_f16(a[m], b[n], acc[m][n], 0, 0, 0);
    __builtin_amdgcn_s_setprio(0);
    // (f,g)
    if (WAITN == 6)      { asm volatile("s_waitcnt vmcnt(6)" ::: "memory"); }
    else if (WAITN == 2) { asm volatile("s_waitcnt vmcnt(2)" ::: "memory"); }
    else if (WAITN == 0) { asm volatile("s_waitcnt vmcnt(0)" ::: "memory"); }
    if (BAR) {
        asm volatile("s_waitcnt lgkmcnt(0)" ::: "memory");
        __builtin_amdgcn_s_barrier();
    }
}

__global__ __launch_bounds__(512, 4)
void gemm_gbn_kernel(const float* __restrict__ Af,
                     const _Float16* __restrict__ Bw,
                     const float* __restrict__ priors,
                     const float* __restrict__ gamma,
                     const float* __restrict__ beta,
                     _Float16* __restrict__ Zh,
                     int M, int N, int K)
{
    __shared__ __align__(16) char lds[81920];   // A 2x16KB + B 3x16KB = 80KB -> 2 blocks/CU

    const int tid  = threadIdx.x;
    const int lane = tid & 63;
    const int wid  = tid >> 6;     // 0..7
    const int wr   = wid >> 2;     // 0..1  (128-row half == one virtual batch)
    const int wc   = wid & 3;      // 0..3  (64-col slice)
    const int fr   = lane & 15;
    const int kg   = lane >> 4;

    // XCD-aware bijective swizzle (512 blocks, %8==0)
    const int bid = blockIdx.x;
    const int swz = (bid & 7) * 64 + (bid >> 3);
    const int row0 = (swz >> 2) * 256;
    const int col0 = (swz & 3) * 256;

    // ---- A fused-cast staging: load j covers row (tid>>3)+j*64, fp32 granule (tid&7) ----
    const float* aBase = Af + (size_t)(row0 + (tid >> 3)) * (size_t)K + (tid & 7) * 4;
    const size_t aRowStep = (size_t)64 * K;
    int wA[4];
    {
        const int sub = tid & 7;
        #pragma unroll
        for (int j = 0; j < 4; ++j) {
            const int r = (tid >> 3) + j * 64;
            wA[j] = r * 64 + (((sub >> 1) ^ ((r >> 1) & 3)) * 16) + (sub & 1) * 8;
        }
    }

    // ---- B staging (proven gload_lds path) ----
    const int bperm = ((tid & 3) ^ ((tid >> 3) & 3)) * 16;
    const char* b0 = (const char*)Bw + (size_t)(col0 + (tid >> 2)) * (size_t)K * 2 + bperm;
    const char* b1 = b0 + (size_t)128 * K * 2;
    const int widB = wid * 1024;

    // ---- fragment read offsets ([256][32] f16, 64B rows, measured-0-conflict swizzle) ----
    int aoff = (wr * 128 + fr) * 64 + kg * 16;
    aoff ^= ((aoff >> 7) & 3) << 4;
    int boff = (wc * 64 + fr) * 64 + kg * 16;
    boff ^= ((boff >> 7) & 3) << 4;

    f32x4 acc[8][4];
    #pragma unroll
    for (int m = 0; m < 8; ++m)
        #pragma unroll
        for (int n = 0; n < 4; ++n)
            acc[m][n] = (f32x4)0.0f;

    const int nt = K >> 5;   // 64 K-tiles of 32 (even)
    f32x4 rA0[4], rA1[4];

    // ---- prologue: A(0),B(0); A(1),B(1); cvt+write A(0); A(2); vmcnt(10) [retires B(0)] ----
    #pragma unroll
    for (int j = 0; j < 4; ++j) rA0[j] = *(const f32x4*)(aBase + j * aRowStep);
    { char* d = BBUF(0) + widB; async16(b0, d); async16(b1, d + 8192); }
    #pragma unroll
    for (int j = 0; j < 4; ++j) rA1[j] = *(const f32x4*)(aBase + j * aRowStep + 32);
    { char* d = BBUF(1) + widB; async16(b0 + 64, d); async16(b1 + 64, d + 8192); }
    #pragma unroll
    for (int j = 0; j < 4; ++j) cvtWrite(ABUF(0) + wA[j], rA0[j]);   // waits A(0) only
    #pragma unroll
    for (int j = 0; j < 4; ++j) rA0[j] = *(const f32x4*)(aBase + j * aRowStep + 64);
    asm volatile("s_waitcnt vmcnt(10)" ::: "memory");   // retires B(0)
    asm volatile("s_waitcnt lgkmcnt(0)" ::: "memory");
    __builtin_amdgcn_s_barrier();

    // ---- main loop: even kt uses rA1 (holds A(kt+1)), odd kt uses rA0 ----
    int kt = 0;
    for (; kt + 5 < nt; kt += 2) {
        ktile<6, true, true, true, true>(kt,     lds, aBase, aRowStep, b0, b1, widB, aoff, boff, wA, rA1, acc);
        ktile<6, true, true, true, true>(kt + 1, lds, aBase, aRowStep, b0, b1, widB, aoff, boff, wA, rA0, acc);
    }
    ktile<6,  true,  true,  true,  true >(nt - 4, lds, aBase, aRowStep, b0, b1, widB, aoff, boff, wA, rA1, acc);
    ktile<2,  false, true,  true,  true >(nt - 3, lds, aBase, aRowStep, b0, b1, widB, aoff, boff, wA, rA0, acc);
    ktile<0,  false, false, true,  true >(nt - 2, lds, aBase, aRowStep, b0, b1, widB, aoff, boff, wA, rA1, acc);
    ktile<-1, false, false, false, false>(nt - 1, lds, aBase, aRowStep, b0, b1, widB, aoff, boff, wA, rA0, acc);

    // ---- fused Ghost BatchNorm + priors epilogue (wave-local; z written f16) ----
    #pragma unroll
    for (int n = 0; n < 4; ++n) {
        float s1 = 0.f, s2 = 0.f;
        #pragma unroll
        for (int m = 0; m < 8; ++m)
            #pragma unroll
            for (int j = 0; j < 4; ++j) {
                float v = acc[m][n][j];
                s1 += v; s2 += v * v;
            }
        s1 += __shfl_xor(s1, 16); s2 += __shfl_xor(s2, 16);
        s1 += __shfl_xor(s1, 32); s2 += __shfl_xor(s2, 32);
        float mean = s1 * (1.f / 128.f);
        float var  = s2 * (1.f / 128.f) - mean * mean;
        float rstd = rsqrtf(var + BN_EPS);
        const int c = col0 + wc * 64 + n * 16 + fr;
        float g = gamma[c] * rstd;
        float b = beta[c] - mean * g;
        #pragma unroll
        for (int m = 0; m < 8; ++m)
            #pragma unroll
            for (int j = 0; j < 4; ++j) {
                int r = row0 + wr * 128 + m * 16 + kg * 4 + j;
                size_t off = (size_t)r * N + c;
                Zh[off] = (_Float16)((acc[m][n][j] * g + b) * priors[off]);
            }
    }
}

// ---------------- sparsemax: one wave per row (1024), f16 input, exact Michelot ----------------
__device__ __forceinline__ float waveSum(float v) {
    #pragma unroll
    for (int off = 32; off > 0; off >>= 1) v += __shfl_xor(v, off);
    return v;
}

__global__ __launch_bounds__(256)
void sparsemax_kernel(const _Float16* __restrict__ Zh, float* __restrict__ Out) {
    const int lane = threadIdx.x & 63;
    const int wid  = threadIdx.x >> 6;
    const size_t row = (size_t)blockIdx.x * 4 + wid;
    const f16x8* zr = (const f16x8*)(Zh + row * 1024);

    float p[16];
    #pragma unroll
    for (int j = 0; j < 2; ++j) {
        f16x8 v = zr[lane * 2 + j];
        #pragma unroll
        for (int e = 0; e < 8; ++e) p[8 * j + e] = (float)v[e];
    }

    float s = 0.f;
    #pragma unroll
    for (int i = 0; i < 16; ++i) s += p[i];
    s = waveSum(s);

    float kc  = 1024.f;
    float tau = (s - 1.f) * (1.f / 1024.f);
    for (int it = 0; it < 64; ++it) {
        float s2 = 0.f, c2 = 0.f;
        #pragma unroll
        for (int i = 0; i < 16; ++i) {
            if (p[i] > tau) { s2 += p[i]; c2 += 1.f; }
        }
        s2 = waveSum(s2); c2 = waveSum(c2);
        if (c2 == kc) break;        // support stable -> tau exact
        kc = c2;
        tau = (s2 - 1.f) / c2;
    }

    float* outr = Out + row * 1024 + lane * 16;
    #pragma unroll
    for (int j = 0; j < 4; ++j) {
        float4 o;
        o.x = fmaxf(p[4 * j + 0] - tau, 0.f);
        o.y = fmaxf(p[4 * j + 1] - tau, 0.f);
        o.z = fmaxf(p[4 * j + 2] - tau, 0.f);
        o.w = fmaxf(p[4 * j + 3] - tau, 0.f);
        *(float4*)(outr + 4 * j) = o;
    }
}

extern "C" void kernel_launch(void* const* d_in, const int* in_sizes, int n_in,
                              void* d_out, int out_size, void* d_ws, size_t ws_size,
                              hipStream_t stream)
{
    const float* priors = (const float*)d_in[0];
    const float* feat   = (const float*)d_in[1];
    const float* W      = (const float*)d_in[2];
    const float* gamma  = (const float*)d_in[3];
    const float* beta   = (const float*)d_in[4];
    float* out = (float*)d_out;

    const int Nf = in_sizes[3];              // 1024
    const int Kf = in_sizes[2] / Nf;         // 2048
    const int Mr = in_sizes[1] / Kf;         // 32768

    _Float16* Wh = (_Float16*)d_ws;                                   // 4 MB
    _Float16* Zh = (_Float16*)((char*)d_ws + (size_t)Nf * Kf * 2);    // 64 MB

    {
        int n8 = Nf * (Kf / 8);
        cast_f32_f16<<<(n8 + 255) / 256, 256, 0, stream>>>(W, Wh, n8);
    }

    int nblk = (Mr / 256) * (Nf / 256);      // 512, divisible by 8
    gemm_gbn_kernel<<<nblk, 512, 0, stream>>>(feat, Wh, priors, gamma, beta, Zh, Mr, Nf, Kf);

    sparsemax_kernel<<<Mr / 4, 256, 0, stream>>>(Zh, out);
}

// Round 18
// 276.706 us; speedup vs baseline: 8.8034x; 8.8034x over previous
//
#include <hip/hip_runtime.h>
#include <hip/hip_bf16.h>
#include <cstdint>

typedef __attribute__((ext_vector_type(4))) float f32x4;
typedef _Float16 f16x8 __attribute__((ext_vector_type(8)));
typedef _Float16 f16x4 __attribute__((ext_vector_type(4)));

#define BN_EPS 1e-5f

// ---------------- fp32 -> fp16 cast (only W, 4 MB) ----------------
__global__ __launch_bounds__(256)
void cast_f32_f16(const float* __restrict__ src, _Float16* __restrict__ dst, int n8) {
    int i = blockIdx.x * blockDim.x + threadIdx.x;
    if (i >= n8) return;
    const float4* s4 = (const float4*)src;
    float4 a = s4[2 * (size_t)i];
    float4 b = s4[2 * (size_t)i + 1];
    f16x8 h;
    h[0] = (_Float16)a.x; h[1] = (_Float16)a.y; h[2] = (_Float16)a.z; h[3] = (_Float16)a.w;
    h[4] = (_Float16)b.x; h[5] = (_Float16)b.y; h[6] = (_Float16)b.z; h[7] = (_Float16)b.w;
    *(f16x8*)(dst + 8 * (size_t)i) = h;
}

// async global->LDS, 16B per lane, wave-uniform LDS base (B path)
__device__ __forceinline__ void async16(const char* g, char* l) {
    __builtin_amdgcn_global_load_lds(
        (const __attribute__((address_space(1))) unsigned int*)(uintptr_t)g,
        (__attribute__((address_space(3))) unsigned int*)(uintptr_t)l,
        16, 0, 0);
}

// ====== r16 (measured best, 276us): 256x256, BK=32, depth-2 prefetch both operands ======
// A regs double-buffered (rA0/rA1), B 4 LDS bufs. NOTE r17 lesson: do NOT raise the
// launch_bounds min-waves arg — 4 waves/SIMD caps the unified reg file at 128/lane,
// which acc[8][4] alone consumes -> accumulator spills to scratch (FETCH 3.7GB, 9x slower).
// FIFO ledger per wave (A=4 reg loads, B=2 asyncs), iteration kt:
//   entering: [A(kt+1)4, B(kt+1)2, A(kt+2)4, B(kt+2)2] = 12 outstanding
//   (a) cvt+ds_write A(kt+1) from rA[s]   [compiler waits vmcnt(8) -> retires A(kt+1)]
//   (b) issue A(kt+3) -> rA[s]  (c) issue B(kt+3) -> BBUF((kt+3)%4)  [14 outstanding]
//   (d) 12 ds_read frags(kt)  (e) 32 MFMA (setprio)
//   (f) vmcnt(12) retires B(kt+1)  (g) lgkmcnt(0) [A-writes visible]; barrier
// WAR: ds_write@kt -> ABUF((kt+1)%3), last read @kt-2, drained 2 barriers ago. B async@kt ->
// BBUF((kt+3)%4)=BBUF((kt-1)%4), last read @kt-1, all waves past barrier@kt-1. Safe.
// Tails (nt even): nt-3 vmcnt(6); nt-2 vmcnt(0); nt-1 compute only.

#define ABUF(t) (lds + ((t) % 3) * 16384)
#define BBUF(t) (lds + 49152 + ((t) % 4) * 16384)

__device__ __forceinline__ void cvtWrite(char* addr, const f32x4& v) {
    f16x4 h;
    h[0] = (_Float16)v[0]; h[1] = (_Float16)v[1];
    h[2] = (_Float16)v[2]; h[3] = (_Float16)v[3];
    *(f16x4*)addr = h;
}

template<int WAITN, bool STAGE, bool WRITEA, bool BAR>
__device__ __forceinline__ void ktile(
    int kt, char* lds, const float* aBase, size_t aRowStep,
    const char* b0, const char* b1, int widB,
    int aoff, int boff, const int (&wA)[4], f32x4 (&rAs)[4],
    f32x4 (&acc)[8][4])
{
    // (a) cvt + ds_write A(kt+1)
    if (WRITEA) {
        char* ad = ABUF(kt + 1);
        #pragma unroll
        for (int j = 0; j < 4; ++j) cvtWrite(ad + wA[j], rAs[j]);
    }
    // (b,c) issue tile kt+3 staging (A into the slot just consumed)
    if (STAGE) {
        #pragma unroll
        for (int j = 0; j < 4; ++j)
            rAs[j] = *(const f32x4*)(aBase + j * aRowStep + (size_t)(kt + 3) * 32);
        char* d = BBUF(kt + 3) + widB;
        async16(b0 + (size_t)(kt + 3) * 64, d);
        async16(b1 + (size_t)(kt + 3) * 64, d + 8192);
    }
    // (d) fragment reads
    f16x8 a[8], b[4];
    const char* ab = ABUF(kt);
    const char* bb = BBUF(kt);
    #pragma unroll
    for (int n = 0; n < 4; ++n) b[n] = *(const f16x8*)(bb + boff + n * 1024);
    #pragma unroll
    for (int m = 0; m < 8; ++m) a[m] = *(const f16x8*)(ab + aoff + m * 1024);
    // (e) MFMA
    __builtin_amdgcn_s_setprio(1);
    #pragma unroll
    for (int m = 0; m < 8; ++m)
        #pragma unroll
        for (int n = 0; n < 4; ++n)
            acc[m][n] = __builtin_amdgcn_mfma_f32_16x16x32_f16(a[m], b[n], acc[m][n], 0, 0, 0);
    __builtin_amdgcn_s_setprio(0);
    // (f,g)
    if (WAITN == 12)     { asm volatile("s_waitcnt vmcnt(12)" ::: "memory"); }
    else if (WAITN == 6) { asm volatile("s_waitcnt vmcnt(6)" ::: "memory"); }
    else if (WAITN == 0) { asm volatile("s_waitcnt vmcnt(0)" ::: "memory"); }
    if (BAR) {
        asm volatile("s_waitcnt lgkmcnt(0)" ::: "memory");
        __builtin_amdgcn_s_barrier();
    }
}

__global__ __launch_bounds__(512, 2)
void gemm_gbn_kernel(const float* __restrict__ Af,
                     const _Float16* __restrict__ Bw,
                     const float* __restrict__ priors,
                     const float* __restrict__ gamma,
                     const float* __restrict__ beta,
                     _Float16* __restrict__ Zh,
                     int M, int N, int K)
{
    __shared__ __align__(16) char lds[114688];   // A 3x16KB + B 4x16KB

    const int tid  = threadIdx.x;
    const int lane = tid & 63;
    const int wid  = tid >> 6;     // 0..7
    const int wr   = wid >> 2;     // 0..1  (128-row half == one virtual batch)
    const int wc   = wid & 3;      // 0..3  (64-col slice)
    const int fr   = lane & 15;
    const int kg   = lane >> 4;

    // XCD-aware bijective swizzle (512 blocks, %8==0)
    const int bid = blockIdx.x;
    const int swz = (bid & 7) * 64 + (bid >> 3);
    const int row0 = (swz >> 2) * 256;
    const int col0 = (swz & 3) * 256;

    // ---- A fused-cast staging: load j covers row (tid>>3)+j*64, fp32 granule (tid&7) ----
    const float* aBase = Af + (size_t)(row0 + (tid >> 3)) * (size_t)K + (tid & 7) * 4;
    const size_t aRowStep = (size_t)64 * K;
    int wA[4];
    {
        const int sub = tid & 7;
        #pragma unroll
        for (int j = 0; j < 4; ++j) {
            const int r = (tid >> 3) + j * 64;
            wA[j] = r * 64 + (((sub >> 1) ^ ((r >> 1) & 3)) * 16) + (sub & 1) * 8;
        }
    }

    // ---- B staging (proven gload_lds path) ----
    const int bperm = ((tid & 3) ^ ((tid >> 3) & 3)) * 16;
    const char* b0 = (const char*)Bw + (size_t)(col0 + (tid >> 2)) * (size_t)K * 2 + bperm;
    const char* b1 = b0 + (size_t)128 * K * 2;
    const int widB = wid * 1024;

    // ---- fragment read offsets ([256][32] f16, 64B rows, measured-0-conflict swizzle) ----
    int aoff = (wr * 128 + fr) * 64 + kg * 16;
    aoff ^= ((aoff >> 7) & 3) << 4;
    int boff = (wc * 64 + fr) * 64 + kg * 16;
    boff ^= ((boff >> 7) & 3) << 4;

    f32x4 acc[8][4];
    #pragma unroll
    for (int m = 0; m < 8; ++m)
        #pragma unroll
        for (int n = 0; n < 4; ++n)
            acc[m][n] = (f32x4)0.0f;

    const int nt = K >> 5;   // 64 K-tiles of 32 (even)
    f32x4 rA0[4], rA1[4];

    // ---- prologue: A(0)->rA0, B(0); A(1)->rA1, B(1); write A(0); A(2)->rA0; B(2) ----
    #pragma unroll
    for (int j = 0; j < 4; ++j) rA0[j] = *(const f32x4*)(aBase + j * aRowStep);
    { char* d = BBUF(0) + widB; async16(b0, d); async16(b1, d + 8192); }
    #pragma unroll
    for (int j = 0; j < 4; ++j) rA1[j] = *(const f32x4*)(aBase + j * aRowStep + 32);
    { char* d = BBUF(1) + widB; async16(b0 + 64, d); async16(b1 + 64, d + 8192); }
    #pragma unroll
    for (int j = 0; j < 4; ++j) cvtWrite(ABUF(0) + wA[j], rA0[j]);   // waits A(0) only
    #pragma unroll
    for (int j = 0; j < 4; ++j) rA0[j] = *(const f32x4*)(aBase + j * aRowStep + 64);
    { char* d = BBUF(2) + widB; async16(b0 + 128, d); async16(b1 + 128, d + 8192); }
    asm volatile("s_waitcnt vmcnt(12)" ::: "memory");   // retires B(0)
    asm volatile("s_waitcnt lgkmcnt(0)" ::: "memory");
    __builtin_amdgcn_s_barrier();

    // ---- main loop: slot s(kt)=(kt+1)&1 -> even kt uses rA1, odd kt uses rA0 ----
    int kt = 0;
    for (; kt + 5 < nt; kt += 2) {
        ktile<12, true, true, true>(kt,     lds, aBase, aRowStep, b0, b1, widB, aoff, boff, wA, rA1, acc);
        ktile<12, true, true, true>(kt + 1, lds, aBase, aRowStep, b0, b1, widB, aoff, boff, wA, rA0, acc);
    }
    // kt == nt-4 (even): steady, stages nt-1
    ktile<12, true,  true,  true >(nt - 4, lds, aBase, aRowStep, b0, b1, widB, aoff, boff, wA, rA1, acc);
    ktile<6,  false, true,  true >(nt - 3, lds, aBase, aRowStep, b0, b1, widB, aoff, boff, wA, rA0, acc);
    ktile<0,  false, true,  true >(nt - 2, lds, aBase, aRowStep, b0, b1, widB, aoff, boff, wA, rA1, acc);
    ktile<-1, false, false, false>(nt - 1, lds, aBase, aRowStep, b0, b1, widB, aoff, boff, wA, rA0, acc);

    // ---- fused Ghost BatchNorm + priors epilogue (wave-local; z written f16) ----
    #pragma unroll
    for (int n = 0; n < 4; ++n) {
        float s1 = 0.f, s2 = 0.f;
        #pragma unroll
        for (int m = 0; m < 8; ++m)
            #pragma unroll
            for (int j = 0; j < 4; ++j) {
                float v = acc[m][n][j];
                s1 += v; s2 += v * v;
            }
        s1 += __shfl_xor(s1, 16); s2 += __shfl_xor(s2, 16);
        s1 += __shfl_xor(s1, 32); s2 += __shfl_xor(s2, 32);
        float mean = s1 * (1.f / 128.f);
        float var  = s2 * (1.f / 128.f) - mean * mean;
        float rstd = rsqrtf(var + BN_EPS);
        const int c = col0 + wc * 64 + n * 16 + fr;
        float g = gamma[c] * rstd;
        float b = beta[c] - mean * g;
        #pragma unroll
        for (int m = 0; m < 8; ++m)
            #pragma unroll
            for (int j = 0; j < 4; ++j) {
                int r = row0 + wr * 128 + m * 16 + kg * 4 + j;
                size_t off = (size_t)r * N + c;
                Zh[off] = (_Float16)((acc[m][n][j] * g + b) * priors[off]);
            }
    }
}

// ---------------- sparsemax: one wave per row (1024), f16 input, exact Michelot ----------------
__device__ __forceinline__ float waveSum(float v) {
    #pragma unroll
    for (int off = 32; off > 0; off >>= 1) v += __shfl_xor(v, off);
    return v;
}

__global__ __launch_bounds__(256)
void sparsemax_kernel(const _Float16* __restrict__ Zh, float* __restrict__ Out) {
    const int lane = threadIdx.x & 63;
    const int wid  = threadIdx.x >> 6;
    const size_t row = (size_t)blockIdx.x * 4 + wid;
    const f16x8* zr = (const f16x8*)(Zh + row * 1024);

    float p[16];
    #pragma unroll
    for (int j = 0; j < 2; ++j) {
        f16x8 v = zr[lane * 2 + j];
        #pragma unroll
        for (int e = 0; e < 8; ++e) p[8 * j + e] = (float)v[e];
    }

    float s = 0.f;
    #pragma unroll
    for (int i = 0; i < 16; ++i) s += p[i];
    s = waveSum(s);

    float kc  = 1024.f;
    float tau = (s - 1.f) * (1.f / 1024.f);
    for (int it = 0; it < 64; ++it) {
        float s2 = 0.f, c2 = 0.f;
        #pragma unroll
        for (int i = 0; i < 16; ++i) {
            if (p[i] > tau) { s2 += p[i]; c2 += 1.f; }
        }
        s2 = waveSum(s2); c2 = waveSum(c2);
        if (c2 == kc) break;        // support stable -> tau exact
        kc = c2;
        tau = (s2 - 1.f) / c2;
    }

    float* outr = Out + row * 1024 + lane * 16;
    #pragma unroll
    for (int j = 0; j < 4; ++j) {
        float4 o;
        o.x = fmaxf(p[4 * j + 0] - tau, 0.f);
        o.y = fmaxf(p[4 * j + 1] - tau, 0.f);
        o.z = fmaxf(p[4 * j + 2] - tau, 0.f);
        o.w = fmaxf(p[4 * j + 3] - tau, 0.f);
        *(float4*)(outr + 4 * j) = o;
    }
}

extern "C" void kernel_launch(void* const* d_in, const int* in_sizes, int n_in,
                              void* d_out, int out_size, void* d_ws, size_t ws_size,
                              hipStream_t stream)
{
    const float* priors = (const float*)d_in[0];
    const float* feat   = (const float*)d_in[1];
    const float* W      = (const float*)d_in[2];
    const float* gamma  = (const float*)d_in[3];
    const float* beta   = (const float*)d_in[4];
    float* out = (float*)d_out;

    const int Nf = in_sizes[3];              // 1024
    const int Kf = in_sizes[2] / Nf;         // 2048
    const int Mr = in_sizes[1] / Kf;         // 32768

    _Float16* Wh = (_Float16*)d_ws;                                   // 4 MB
    _Float16* Zh = (_Float16*)((char*)d_ws + (size_t)Nf * Kf * 2);    // 64 MB

    {
        int n8 = Nf * (Kf / 8);
        cast_f32_f16<<<(n8 + 255) / 256, 256, 0, stream>>>(W, Wh, n8);
    }

    int nblk = (Mr / 256) * (Nf / 256);      // 512, divisible by 8
    gemm_gbn_kernel<<<nblk, 512, 0, stream>>>(feat, Wh, priors, gamma, beta, Zh, Mr, Nf, Kf);

    sparsemax_kernel<<<Mr / 4, 256, 0, stream>>>(Zh, out);
}